// Round 1
// 612.687 us; speedup vs baseline: 1.1208x; 1.1208x over previous
//
#include <hip/hip_runtime.h>

#define B_DIM 64
#define S_DIM 784
#define T_DIM 500
#define N_DIM 1024
#define TP    522
#define KS    21
#define THETA 80
#define NCHUNK 8
#define CH    66
#define LISTCAP 128
#define SW64  13        // ceil(784/64) u64 words per timestep bitmap
#define BMSTRIDE 16     // padded row stride (u64 words) -> 128 B rows

// ---- K1: wt9[s][n] = w ? 9*(w-1) : 63 (shift amount for 64-bit class counters)
__global__ void k_prep(const int* __restrict__ w, unsigned char* __restrict__ wt9) {
  unsigned idx = blockIdx.x * 256 + threadIdx.x;
  if (idx < S_DIM * N_DIM) {
    unsigned s = idx >> 10, n = idx & 1023;
    int wv = w[n * S_DIM + s];
    wt9[idx] = wv ? (unsigned char)(9 * (wv - 1)) : (unsigned char)63;
  }
}

// ---- K2: per-(b,t) spike BITMAPS via double-ballot bit transpose.
//          Zero global atomics (replaces the atomic-bound list builder):
//          phase A: wave reads one s-row x 64 t (coalesced), ballot -> mask over t.
//          phase B: 13 waves re-ballot bit tl of 64 masks -> bits over s.
__global__ void __launch_bounds__(1024)
k_bitmap(const float* __restrict__ x, unsigned long long* __restrict__ bm) {
  __shared__ unsigned long long s_m[S_DIM];
  const int tid = threadIdx.x;
  const int wave = tid >> 6, lane = tid & 63;
  const int b = blockIdx.y;
  const int t0 = blockIdx.x * 64;
  const int t = t0 + lane;
  const bool tok = (t < T_DIM);
  const float* xb = x + (size_t)b * S_DIM * T_DIM;

  for (int s = wave; s < S_DIM; s += 16) {
    float v = tok ? xb[(size_t)s * T_DIM + t] : 0.0f;
    unsigned long long m = __ballot(v != 0.0f);
    if (lane == 0) s_m[s] = m;
  }
  __syncthreads();

  if (wave < SW64) {
    const int sbase = wave * 64;
    const unsigned long long mask_s =
        (sbase + lane < S_DIM) ? s_m[sbase + lane] : 0ull;
    unsigned long long* dst = bm + ((size_t)b * 512 + t0) * BMSTRIDE + wave;
    for (int tl = 0; tl < 64; ++tl) {
      unsigned long long wrd = __ballot((mask_s >> tl) & 1ull);
      if (lane == 0) dst[(size_t)tl * BMSTRIDE] = wrd;
    }
  }
}

// ---- K3: barrier-free fused sparse conv + argmax. One block = (b, time-chunk),
//          one thread = one neuron; 22-deep register ring of partial potentials.
//          Prologue now decodes bitmaps -> LDS spike lists with LDS atomics only.
__global__ void __launch_bounds__(1024, 8)
k_main(const unsigned char* __restrict__ wt9,
       const unsigned long long* __restrict__ bm,
       unsigned* __restrict__ red) {
  __shared__ unsigned short s_list[87][LISTCAP];
  __shared__ int s_cnt[87];
  __shared__ unsigned smax[CH];

  const int tid = threadIdx.x;
  const int b = blockIdx.y;
  const int lo = blockIdx.x * CH;
  const int hi = min(TP - 1, lo + CH - 1);
  const int t0 = max(0, lo - KS);
  const int n_emit = hi - lo + 1;
  const int nt_in = min(hi, T_DIM - 1) - t0 + 1;

  for (int i = tid; i < nt_in; i += 1024) s_cnt[i] = 0;
  for (int i = tid; i < n_emit; i += 1024) smax[i] = 0u;
  __syncthreads();

  // ---- decode bitmap words into spike lists (list order irrelevant: sums commute)
  const unsigned long long* bmb = bm + ((size_t)b * 512 + t0) * BMSTRIDE;
  const int ntask = nt_in * SW64;
  for (int task = tid; task < ntask; task += 1024) {
    const int li = task / SW64;
    const int sw = task - li * SW64;
    unsigned long long w = bmb[(size_t)li * BMSTRIDE + sw];
    if (w) {
      int c = __popcll(w);
      int pos = atomicAdd(&s_cnt[li], c);
      const int sb = sw * 64;
      while (w) {
        int j = __builtin_ctzll(w);
        if (pos < LISTCAP) s_list[li][pos] = (unsigned short)(sb + j);
        ++pos;
        w &= (w - 1);
      }
    }
  }
  __syncthreads();

  int ring[KS + 1];
  #pragma unroll
  for (int i = 0; i <= KS; ++i) ring[i] = 0;

  const unsigned invn = (unsigned)(1023 - tid);

  for (int t = t0; t <= hi; ++t) {
    // per-t argmax: wave-local butterfly, then one LDS atomicMax per wave (no barrier)
    if (t >= lo) {
      unsigned key = ((unsigned)ring[0] << 10) | invn;
      #pragma unroll
      for (int off = 32; off > 0; off >>= 1) {
        unsigned o = __shfl_xor(key, off, 64);
        key = key > o ? key : o;
      }
      if ((tid & 63) == 0) atomicMax(&smax[t - lo], key);
    }

    if (t < T_DIM) {
      const int li = t - t0;
      const int cnt = __builtin_amdgcn_readfirstlane(min(s_cnt[li], LISTCAP));
      const unsigned short* lp = &s_list[li][0];
      unsigned long long ca = 0, cb = 0;   // seven 9-bit class counters (bit63 = w0 garbage)
      int i = 0;
      for (; i + 1 < cnt; i += 2) {
        unsigned ia = ((unsigned)lp[i] << 10) + tid;
        unsigned ib = ((unsigned)lp[i + 1] << 10) + tid;
        ca += 1ull << wt9[ia];
        cb += 1ull << wt9[ib];
      }
      if (i < cnt) ca += 1ull << wt9[((unsigned)lp[i] << 10) + tid];
      const unsigned long long c = ca + cb;

      const int c1 = (int)(c & 511), c2 = (int)((c >> 9) & 511), c3 = (int)((c >> 18) & 511),
                c4 = (int)((c >> 27) & 511), c5 = (int)((c >> 36) & 511),
                c6 = (int)((c >> 45) & 511), c7 = (int)((c >> 54) & 511);
      // response-table application as running-delta adds (63 single-slot ops, no muls):
      const int S7 = c7, S6 = S7 + c6, S5 = S6 + c5, S4 = S5 + c4,
                S3 = S4 + c3, S2 = S3 + c2, S1 = S2 + c1;
      const int O1 = c1, O3 = O1 + c3, O5 = O3 + c5, O7 = O5 + c7;
      const int E2 = c2, E4 = E2 + c4, E6 = E4 + c6;
      const int O31 = O3 - O1, O51 = O5 - O1, O71 = O7 - O1,
                O73 = O7 - O3, O75 = O7 - O5;
      const int E62 = E6 - E2, E64 = E6 - E4;
      int acc = S1;        ring[1]  += acc;
      acc += S2;           ring[2]  += acc;
      acc += S3 - O1;      ring[3]  += acc;
      acc += S4 - E2;      ring[4]  += acc;
      acc += S5 - O31;     ring[5]  += acc;
      acc += S6 - E4;      ring[6]  += acc;
      acc += S7 - O51;     ring[7]  += acc;
      acc -= E62;          ring[8]  += acc;
      acc -= O71;          ring[9]  += acc;
      acc -= E62;          ring[10] += acc;
      acc -= O73;          ring[11] += acc;
      acc -= E62;          ring[12] += acc;
      acc -= O73;          ring[13] += acc;
      acc -= E64;          ring[14] += acc;
      acc -= O73;          ring[15] += acc;
      acc -= E64;          ring[16] += acc;
      acc -= O75;          ring[17] += acc;
      acc -= E64;          ring[18] += acc;
      acc -= O75;          ring[19] += acc;
                           ring[20] += acc;
      acc -= O75;          ring[21] += acc;
    }

    #pragma unroll
    for (int i = 0; i < KS; ++i) ring[i] = ring[i + 1];
    ring[KS] = 0;
  }

  __syncthreads();
  for (int i = tid; i < n_emit; i += 1024)
    red[(unsigned)b * TP + (unsigned)(lo + i)] = smax[i];
}

// ---- K4: winner-take-all dep scan; 6-wide load batching to hide L2 latency
__global__ void k_scan(const unsigned* __restrict__ red, int* __restrict__ out) {
  int b = threadIdx.x;
  if (b >= B_DIM) return;
  int dep = 0;
  for (int base = 0; base < TP; base += 6) {   // 522 = 87*6
    unsigned buf[6];
    #pragma unroll
    for (int k = 0; k < 6; ++k) buf[k] = red[b * TP + base + k];
    #pragma unroll
    for (int k = 0; k < 6; ++k) {
      unsigned key = buf[k];
      int val = (int)(key >> 10);
      bool cond = (val > THETA) && (dep == 0);
      if (cond) {
        int idx = 1023 - (int)(key & 1023);
        out[(b * N_DIM + idx) * TP + base + k] = 1;
        dep = 22;  // FODEP+1
      }
      dep = max(0, dep - 1);
    }
  }
}

extern "C" void kernel_launch(void* const* d_in, const int* in_sizes, int n_in,
                              void* d_out, int out_size, void* d_ws, size_t ws_size,
                              hipStream_t stream) {
  const float* x = (const float*)d_in[0];
  const int* wgt = (const int*)d_in[1];
  int* out = (int*)d_out;

  // workspace layout (total ~5.13 MB)
  unsigned char* wt9      = (unsigned char*)d_ws;                              // 802,816 B
  unsigned long long* bm  = (unsigned long long*)((char*)d_ws + 802816);       // 4,194,304 B
  unsigned* red           = (unsigned*)((char*)d_ws + 802816 + 4194304);       // 133,632 B

  hipMemsetAsync(d_out, 0, (size_t)out_size * sizeof(int), stream);
  k_prep<<<3136, 256, 0, stream>>>(wgt, wt9);
  k_bitmap<<<dim3(8, B_DIM), 1024, 0, stream>>>(x, bm);
  k_main<<<dim3(NCHUNK, B_DIM), 1024, 0, stream>>>(wt9, bm, red);
  k_scan<<<1, 64, 0, stream>>>(red, out);
}